// Round 3
// baseline (805.872 us; speedup 1.0000x reference)
//
#include <hip/hip_runtime.h>
#include <stdint.h>

#define H_DIM 4096
#define I_DIM 11008
#define T_DIM 4096

typedef int i32x4 __attribute__((ext_vector_type(4)));
typedef const void __attribute__((address_space(1))) gvoid_t;
typedef void __attribute__((address_space(3))) svoid_t;

__device__ __forceinline__ void gload_lds16(const void* gsrc, void* ldst) {
    __builtin_amdgcn_global_load_lds((gvoid_t*)gsrc, (svoid_t*)ldst, 16, 0, 0);
}
__device__ __forceinline__ void wait_vmcnt4() {
    asm volatile("s_waitcnt vmcnt(4)" ::: "memory");
}
__device__ __forceinline__ void barrier_() {
    asm volatile("s_barrier" ::: "memory");
}

__device__ __forceinline__ uint32_t pack4(int4 v) {
    uint32_t r = (uint32_t)(uint8_t)v.x;
    r |= (uint32_t)(uint8_t)v.y << 8;
    r |= (uint32_t)(uint8_t)v.z << 16;
    r |= (uint32_t)(uint8_t)v.w << 24;
    return r;
}

// int32 -> int8 pack (truncate low byte; values already int8-range)
__global__ void convert_kernel(const int* __restrict__ src, int8_t* __restrict__ dst,
                               int n4) {
    int idx = blockIdx.x * blockDim.x + threadIdx.x;
    int stride = gridDim.x * blockDim.x;
    for (int i = idx; i < n4; i += stride) {
        int4 v = ((const int4*)src)[i];
        ((uint32_t*)dst)[i] = pack4(v);
    }
}

#define MFMA_I8 __builtin_amdgcn_mfma_i32_16x16x64_i8

// ---------------------------------------------------------------------------
// gateup: BM=256 BN=128 BK=128B, 8 waves (2Mx4N), per-wave 128x32, two accs.
// 4 phases/K-tile, 16 MFMA/phase, counted vmcnt(4), XOR-swizzled LDS.
// ---------------------------------------------------------------------------
__global__ __launch_bounds__(512, 2)
void gateup_kernel(const int8_t* __restrict__ x8, const int8_t* __restrict__ gw8,
                   const int8_t* __restrict__ uw8,
                   const float* __restrict__ galpha, const float* __restrict__ gbias,
                   const float* __restrict__ ualpha, const float* __restrict__ ubias,
                   const float* __restrict__ scale_p, int8_t* __restrict__ hq)
{
    __shared__ __align__(16) int8_t lsA[2][2][256 * 64];  // [buf][kk][row*64+slot]
    __shared__ __align__(16) int8_t lsG[2][2][128 * 64];
    __shared__ __align__(16) int8_t lsU[2][2][128 * 64];

    const int nwg = gridDim.x;                 // 1376 (divisible by 8)
    int bid = blockIdx.x;
    bid = (bid & 7) * (nwg >> 3) + (bid >> 3); // XCD swizzle (bijective: nwg%8==0)
    const int mt = bid & 15;                   // 16 M tiles
    const int nt = bid >> 4;                   // 86 N tiles (consecutive bids share weights)
    const int m0 = mt << 8;
    const int n0 = nt << 7;

    const int tid  = threadIdx.x;
    const int lane = tid & 63;
    const int wid  = tid >> 6;
    const int wr   = wid >> 2;                 // 0..1
    const int wc   = wid & 3;                  // 0..3
    const int lr   = lane & 15;
    const int rdsw = ((lane >> 4) ^ ((lr >> 1) & 3)) << 4;  // read-side XOR slot

    // staging coords (512 lanes cover 128 rows x 64B, source pre-swizzled)
    const int srow = tid >> 2;
    const int scol = ((tid & 3) ^ ((tid >> 3) & 3)) << 4;
    const int woff = wid << 10;

    const int8_t* As = x8  + (size_t)(m0 + srow) * H_DIM + scol;
    const int8_t* Gs = gw8 + (size_t)(n0 + srow) * H_DIM + scol;
    const int8_t* Us = uw8 + (size_t)(n0 + srow) * H_DIM + scol;

    i32x4 accg[8][2], accu[8][2];
#pragma unroll
    for (int mf = 0; mf < 8; ++mf)
#pragma unroll
        for (int nf = 0; nf < 2; ++nf) {
            accg[mf][nf] = i32x4{0, 0, 0, 0};
            accu[mf][nf] = i32x4{0, 0, 0, 0};
        }

    const int aro = (wr * 128 + lr) * 64 + rdsw;   // + mf*1024
    const int gro = (wc * 32 + lr) * 64 + rdsw;    // + nf*1024

#define STA(buf, kk, rh, kb) gload_lds16(As + (size_t)(rh) * 128 * H_DIM + (kb) + (kk) * 64, \
                                         &lsA[buf][kk][(rh) * 8192 + woff])
#define STG(buf, kk, kb)     gload_lds16(Gs + (kb) + (kk) * 64, &lsG[buf][kk][woff])
#define STU(buf, kk, kb)     gload_lds16(Us + (kb) + (kk) * 64, &lsU[buf][kk][woff])

    // prologue: tile 0 -> buf 0 (kk0 group first, then kk1)
    STA(0, 0, 0, 0); STA(0, 0, 1, 0); STG(0, 0, 0); STU(0, 0, 0);
    STA(0, 1, 0, 0); STA(0, 1, 1, 0); STG(0, 1, 0); STU(0, 1, 0);
    wait_vmcnt4();
    barrier_();

    const int NKT = H_DIM / 128;  // 32
    for (int t = 0; t < NKT; ++t) {
        const int cur = t & 1, nxt = cur ^ 1;
        const int kbn = ((t + 1 < NKT) ? (t + 1) : 0) << 7;
        i32x4 a[4], bg[2], bu[2];
        // ---- phase 0: kk0, mf0-3 ----
        STA(nxt, 0, 0, kbn); STA(nxt, 0, 1, kbn);
        bg[0] = *(const i32x4*)&lsG[cur][0][gro];
        bg[1] = *(const i32x4*)&lsG[cur][0][gro + 1024];
        bu[0] = *(const i32x4*)&lsU[cur][0][gro];
        bu[1] = *(const i32x4*)&lsU[cur][0][gro + 1024];
#pragma unroll
        for (int mf = 0; mf < 4; ++mf) a[mf] = *(const i32x4*)&lsA[cur][0][aro + mf * 1024];
        __builtin_amdgcn_s_setprio(1);
#pragma unroll
        for (int mf = 0; mf < 4; ++mf) {
            accg[mf][0] = MFMA_I8(a[mf], bg[0], accg[mf][0], 0, 0, 0);
            accg[mf][1] = MFMA_I8(a[mf], bg[1], accg[mf][1], 0, 0, 0);
            accu[mf][0] = MFMA_I8(a[mf], bu[0], accu[mf][0], 0, 0, 0);
            accu[mf][1] = MFMA_I8(a[mf], bu[1], accu[mf][1], 0, 0, 0);
        }
        __builtin_amdgcn_s_setprio(0);
        // ---- phase 1: kk0, mf4-7 ----
        STG(nxt, 0, kbn); STU(nxt, 0, kbn);
#pragma unroll
        for (int mf = 0; mf < 4; ++mf) a[mf] = *(const i32x4*)&lsA[cur][0][aro + (mf + 4) * 1024];
        __builtin_amdgcn_s_setprio(1);
#pragma unroll
        for (int mf = 0; mf < 4; ++mf) {
            accg[mf + 4][0] = MFMA_I8(a[mf], bg[0], accg[mf + 4][0], 0, 0, 0);
            accg[mf + 4][1] = MFMA_I8(a[mf], bg[1], accg[mf + 4][1], 0, 0, 0);
            accu[mf + 4][0] = MFMA_I8(a[mf], bu[0], accu[mf + 4][0], 0, 0, 0);
            accu[mf + 4][1] = MFMA_I8(a[mf], bu[1], accu[mf + 4][1], 0, 0, 0);
        }
        __builtin_amdgcn_s_setprio(0);
        wait_vmcnt4();   // kk1 of tile t landed (staged 4..8 calls back)
        barrier_();
        // ---- phase 2: kk1, mf0-3 ----
        STA(nxt, 1, 0, kbn); STA(nxt, 1, 1, kbn);
        bg[0] = *(const i32x4*)&lsG[cur][1][gro];
        bg[1] = *(const i32x4*)&lsG[cur][1][gro + 1024];
        bu[0] = *(const i32x4*)&lsU[cur][1][gro];
        bu[1] = *(const i32x4*)&lsU[cur][1][gro + 1024];
#pragma unroll
        for (int mf = 0; mf < 4; ++mf) a[mf] = *(const i32x4*)&lsA[cur][1][aro + mf * 1024];
        __builtin_amdgcn_s_setprio(1);
#pragma unroll
        for (int mf = 0; mf < 4; ++mf) {
            accg[mf][0] = MFMA_I8(a[mf], bg[0], accg[mf][0], 0, 0, 0);
            accg[mf][1] = MFMA_I8(a[mf], bg[1], accg[mf][1], 0, 0, 0);
            accu[mf][0] = MFMA_I8(a[mf], bu[0], accu[mf][0], 0, 0, 0);
            accu[mf][1] = MFMA_I8(a[mf], bu[1], accu[mf][1], 0, 0, 0);
        }
        __builtin_amdgcn_s_setprio(0);
        // ---- phase 3: kk1, mf4-7 ----
        STG(nxt, 1, kbn); STU(nxt, 1, kbn);
#pragma unroll
        for (int mf = 0; mf < 4; ++mf) a[mf] = *(const i32x4*)&lsA[cur][1][aro + (mf + 4) * 1024];
        __builtin_amdgcn_s_setprio(1);
#pragma unroll
        for (int mf = 0; mf < 4; ++mf) {
            accg[mf + 4][0] = MFMA_I8(a[mf], bg[0], accg[mf + 4][0], 0, 0, 0);
            accg[mf + 4][1] = MFMA_I8(a[mf], bg[1], accg[mf + 4][1], 0, 0, 0);
            accu[mf + 4][0] = MFMA_I8(a[mf], bu[0], accu[mf + 4][0], 0, 0, 0);
            accu[mf + 4][1] = MFMA_I8(a[mf], bu[1], accu[mf + 4][1], 0, 0, 0);
        }
        __builtin_amdgcn_s_setprio(0);
        wait_vmcnt4();   // kk0 of tile t+1 landed
        barrier_();
    }
#undef STA
#undef STG
#undef STU

    // epilogue: dequant, SwiGLU, requant
    const float scale = *scale_p;
#pragma unroll
    for (int nf = 0; nf < 2; ++nf) {
        const int col = n0 + wc * 32 + nf * 16 + lr;
        const float gA = galpha[col], gB = gbias[col];
        const float uA = ualpha[col], uB = ubias[col];
#pragma unroll
        for (int mf = 0; mf < 8; ++mf) {
            const int row0 = m0 + wr * 128 + mf * 16 + (lane >> 4) * 4;
#pragma unroll
            for (int j = 0; j < 4; ++j) {
                float g = (float)accg[mf][nf][j] * gA + gB;
                float u = (float)accu[mf][nf][j] * uA + uB;
                float s = 1.0f / (1.0f + __expf(-g));
                float h = g * s * u;
                float q = rintf(h / scale);
                q = fminf(127.0f, fmaxf(-128.0f, q));
                hq[(size_t)(row0 + j) * I_DIM + col] = (int8_t)q;
            }
        }
    }
}

// ---------------------------------------------------------------------------
// down: BM=256 BN=256 BK=128B, 8 waves (2Mx4N), per-wave 128x64.
// ---------------------------------------------------------------------------
__global__ __launch_bounds__(512, 2)
void down_kernel(const int8_t* __restrict__ hq, const int8_t* __restrict__ dw8,
                 const float* __restrict__ dalpha, const float* __restrict__ dbias,
                 float* __restrict__ out)
{
    __shared__ __align__(16) int8_t lsA[2][2][256 * 64];
    __shared__ __align__(16) int8_t lsB[2][2][256 * 64];

    const int nwg = gridDim.x;                 // 256
    int bid = blockIdx.x;
    bid = (bid & 7) * (nwg >> 3) + (bid >> 3);
    const int mt = bid & 15;
    const int nt = bid >> 4;
    const int m0 = mt << 8;
    const int n0 = nt << 8;

    const int tid  = threadIdx.x;
    const int lane = tid & 63;
    const int wid  = tid >> 6;
    const int wr   = wid >> 2;
    const int wc   = wid & 3;
    const int lr   = lane & 15;
    const int rdsw = ((lane >> 4) ^ ((lr >> 1) & 3)) << 4;

    const int srow = tid >> 2;
    const int scol = ((tid & 3) ^ ((tid >> 3) & 3)) << 4;
    const int woff = wid << 10;

    const int8_t* As = hq  + (size_t)(m0 + srow) * I_DIM + scol;
    const int8_t* Bs = dw8 + (size_t)(n0 + srow) * I_DIM + scol;

    i32x4 acc[8][4];
#pragma unroll
    for (int mf = 0; mf < 8; ++mf)
#pragma unroll
        for (int nf = 0; nf < 4; ++nf) acc[mf][nf] = i32x4{0, 0, 0, 0};

    const int aro = (wr * 128 + lr) * 64 + rdsw;   // + mf*1024
    const int bro = (wc * 64 + lr) * 64 + rdsw;    // + nf*1024

#define SDA(buf, kk, rh, kb) gload_lds16(As + (size_t)(rh) * 128 * I_DIM + (kb) + (kk) * 64, \
                                         &lsA[buf][kk][(rh) * 8192 + woff])
#define SDB(buf, kk, rh, kb) gload_lds16(Bs + (size_t)(rh) * 128 * I_DIM + (kb) + (kk) * 64, \
                                         &lsB[buf][kk][(rh) * 8192 + woff])

    SDA(0, 0, 0, 0); SDA(0, 0, 1, 0); SDB(0, 0, 0, 0); SDB(0, 0, 1, 0);
    SDA(0, 1, 0, 0); SDA(0, 1, 1, 0); SDB(0, 1, 0, 0); SDB(0, 1, 1, 0);
    wait_vmcnt4();
    barrier_();

    const int NKT = I_DIM / 128;  // 86
    for (int t = 0; t < NKT; ++t) {
        const int cur = t & 1, nxt = cur ^ 1;
        const int kbn = ((t + 1 < NKT) ? (t + 1) : 0) << 7;
        i32x4 a[4], b[4];
        // ---- phase 0: kk0, mf0-3 ----
        SDA(nxt, 0, 0, kbn); SDA(nxt, 0, 1, kbn);
#pragma unroll
        for (int nf = 0; nf < 4; ++nf) b[nf] = *(const i32x4*)&lsB[cur][0][bro + nf * 1024];
#pragma unroll
        for (int mf = 0; mf < 4; ++mf) a[mf] = *(const i32x4*)&lsA[cur][0][aro + mf * 1024];
        __builtin_amdgcn_s_setprio(1);
#pragma unroll
        for (int mf = 0; mf < 4; ++mf)
#pragma unroll
            for (int nf = 0; nf < 4; ++nf)
                acc[mf][nf] = MFMA_I8(a[mf], b[nf], acc[mf][nf], 0, 0, 0);
        __builtin_amdgcn_s_setprio(0);
        // ---- phase 1: kk0, mf4-7 ----
        SDB(nxt, 0, 0, kbn); SDB(nxt, 0, 1, kbn);
#pragma unroll
        for (int mf = 0; mf < 4; ++mf) a[mf] = *(const i32x4*)&lsA[cur][0][aro + (mf + 4) * 1024];
        __builtin_amdgcn_s_setprio(1);
#pragma unroll
        for (int mf = 0; mf < 4; ++mf)
#pragma unroll
            for (int nf = 0; nf < 4; ++nf)
                acc[mf + 4][nf] = MFMA_I8(a[mf], b[nf], acc[mf + 4][nf], 0, 0, 0);
        __builtin_amdgcn_s_setprio(0);
        wait_vmcnt4();
        barrier_();
        // ---- phase 2: kk1, mf0-3 ----
        SDA(nxt, 1, 0, kbn); SDA(nxt, 1, 1, kbn);
#pragma unroll
        for (int nf = 0; nf < 4; ++nf) b[nf] = *(const i32x4*)&lsB[cur][1][bro + nf * 1024];
#pragma unroll
        for (int mf = 0; mf < 4; ++mf) a[mf] = *(const i32x4*)&lsA[cur][1][aro + mf * 1024];
        __builtin_amdgcn_s_setprio(1);
#pragma unroll
        for (int mf = 0; mf < 4; ++mf)
#pragma unroll
            for (int nf = 0; nf < 4; ++nf)
                acc[mf][nf] = MFMA_I8(a[mf], b[nf], acc[mf][nf], 0, 0, 0);
        __builtin_amdgcn_s_setprio(0);
        // ---- phase 3: kk1, mf4-7 ----
        SDB(nxt, 1, 0, kbn); SDB(nxt, 1, 1, kbn);
#pragma unroll
        for (int mf = 0; mf < 4; ++mf) a[mf] = *(const i32x4*)&lsA[cur][1][aro + (mf + 4) * 1024];
        __builtin_amdgcn_s_setprio(1);
#pragma unroll
        for (int mf = 0; mf < 4; ++mf)
#pragma unroll
            for (int nf = 0; nf < 4; ++nf)
                acc[mf + 4][nf] = MFMA_I8(a[mf], b[nf], acc[mf + 4][nf], 0, 0, 0);
        __builtin_amdgcn_s_setprio(0);
        wait_vmcnt4();
        barrier_();
    }
#undef SDA
#undef SDB

#pragma unroll
    for (int nf = 0; nf < 4; ++nf) {
        const int col = n0 + wc * 64 + nf * 16 + lr;
        const float dA = dalpha[col], dB = dbias[col];
#pragma unroll
        for (int mf = 0; mf < 8; ++mf) {
            const int row0 = m0 + wr * 128 + mf * 16 + (lane >> 4) * 4;
#pragma unroll
            for (int j = 0; j < 4; ++j) {
                out[(size_t)(row0 + j) * H_DIM + col] = (float)acc[mf][nf][j] * dA + dB;
            }
        }
    }
}

extern "C" void kernel_launch(void* const* d_in, const int* in_sizes, int n_in,
                              void* d_out, int out_size, void* d_ws, size_t ws_size,
                              hipStream_t stream) {
    const int* x32  = (const int*)d_in[0];
    const int* gw32 = (const int*)d_in[1];
    const int* uw32 = (const int*)d_in[2];
    const int* dw32 = (const int*)d_in[3];
    const float* ga = (const float*)d_in[4];
    const float* gb = (const float*)d_in[5];
    const float* ua = (const float*)d_in[6];
    const float* ub = (const float*)d_in[7];
    const float* da = (const float*)d_in[8];
    const float* db = (const float*)d_in[9];
    const float* sc = (const float*)d_in[10];
    float* out = (float*)d_out;

    const size_t SZ_X8 = (size_t)T_DIM * H_DIM;
    const size_t SZ_W  = (size_t)I_DIM * H_DIM;
    const size_t SZ_HQ = (size_t)T_DIM * I_DIM;

    int8_t* gw8 = (int8_t*)d_ws;              // reused for dw8 later
    int8_t* uw8 = gw8 + SZ_W;
    int8_t* hq  = uw8 + SZ_W;
    int8_t* x8  = hq + SZ_HQ;

    convert_kernel<<<dim3(2048), dim3(256), 0, stream>>>(x32, x8, (int)(SZ_X8 / 4));
    convert_kernel<<<dim3(2048), dim3(256), 0, stream>>>(gw32, gw8, (int)(SZ_W / 4));
    convert_kernel<<<dim3(2048), dim3(256), 0, stream>>>(uw32, uw8, (int)(SZ_W / 4));
    gateup_kernel<<<dim3(16 * 86), dim3(512), 0, stream>>>(
        x8, gw8, uw8, ga, gb, ua, ub, sc, hq);
    int8_t* dw8 = gw8;   // overwrite gate weights (stream-ordered after gateup)
    convert_kernel<<<dim3(2048), dim3(256), 0, stream>>>(dw32, dw8, (int)(SZ_W / 4));
    down_kernel<<<dim3(16 * 16), dim3(512), 0, stream>>>(hq, dw8, da, db, out);
}